// Round 1
// baseline (2408.960 us; speedup 1.0000x reference)
//
#include <hip/hip_runtime.h>
#include <cstddef>

#define TPB 256

// ---------------------------------------------------------------------------
// Degree accumulation: degp[t] += max(w,0); degn[t] += max(-w,0)
// ---------------------------------------------------------------------------
__global__ void deg_kernel(const int* __restrict__ tgt, const float* __restrict__ ew,
                           float* __restrict__ degp, float* __restrict__ degn, int E) {
    int e = blockIdx.x * blockDim.x + threadIdx.x;
    if (e >= E) return;
    float w = ew[e];
    int t = tgt[e];
    if (w > 0.0f)      atomicAdd(&degp[t], w);
    else if (w < 0.0f) atomicAdd(&degn[t], -w);
}

// dinv = rsqrt(deg + 1)  (deg >= 0 so always valid), in place
__global__ void dinv_kernel(float* __restrict__ degp, float* __restrict__ degn, int n) {
    int i = blockIdx.x * blockDim.x + threadIdx.x;
    if (i >= n) return;
    degp[i] = rsqrtf(degp[i] + 1.0f);
    degn[i] = rsqrtf(degn[i] + 1.0f);
}

// ---------------------------------------------------------------------------
// Dual GEMM: hp = x @ Wp^T, hn = x @ Wn^T.  W is [OUTF, IN] row-major.
// One thread per row; x row in VGPRs; W via wave-uniform (scalar) loads.
// blockIdx.y splits the column range in 2 for extra grid parallelism.
// ---------------------------------------------------------------------------
template<int IN, int OUTF>
__global__ void dual_gemm_kernel(const float* __restrict__ x,
                                 const float* __restrict__ Wp, const float* __restrict__ Wn,
                                 float* __restrict__ hp, float* __restrict__ hn, int n) {
    int row = blockIdx.x * blockDim.x + threadIdx.x;
    if (row >= n) return;
    float xr[IN];
    const float4* xp = (const float4*)(x + (size_t)row * IN);
#pragma unroll
    for (int q = 0; q < IN / 4; ++q) {
        float4 v = xp[q];
        xr[4*q+0] = v.x; xr[4*q+1] = v.y; xr[4*q+2] = v.z; xr[4*q+3] = v.w;
    }
    const int c_begin = blockIdx.y * (OUTF / 2);
    const int c_end   = c_begin + (OUTF / 2);
    for (int c = c_begin; c < c_end; c += 4) {
        float ap0 = 0.f, ap1 = 0.f, ap2 = 0.f, ap3 = 0.f;
        float an0 = 0.f, an1 = 0.f, an2 = 0.f, an3 = 0.f;
#pragma unroll 16
        for (int k = 0; k < IN; ++k) {
            float xv = xr[k];
            ap0 += xv * Wp[(size_t)(c+0)*IN + k];
            ap1 += xv * Wp[(size_t)(c+1)*IN + k];
            ap2 += xv * Wp[(size_t)(c+2)*IN + k];
            ap3 += xv * Wp[(size_t)(c+3)*IN + k];
            an0 += xv * Wn[(size_t)(c+0)*IN + k];
            an1 += xv * Wn[(size_t)(c+1)*IN + k];
            an2 += xv * Wn[(size_t)(c+2)*IN + k];
            an3 += xv * Wn[(size_t)(c+3)*IN + k];
        }
        float4 op = {ap0, ap1, ap2, ap3};
        float4 on = {an0, an1, an2, an3};
        *(float4*)(hp + (size_t)row * OUTF + c) = op;
        *(float4*)(hn + (size_t)row * OUTF + c) = on;
    }
}

// ---------------------------------------------------------------------------
// Edge scatter. One wave (64 lanes) per edge.
// For w>0: agg[t] += hp[s] * (dinvp[s]*w*dinvp[t])
// For w<0: agg[t] += hn[s] * (dinvn[s]*w*dinvn[t])   (w<0 supplies the minus)
// ---------------------------------------------------------------------------
template<int F>
__global__ void scatter_kernel(const int* __restrict__ src, const int* __restrict__ tgt,
                               const float* __restrict__ ew,
                               const float* __restrict__ dinvp, const float* __restrict__ dinvn,
                               const float* __restrict__ hp, const float* __restrict__ hn,
                               float* agg, int E) {
    const int lane = threadIdx.x & 63;
    int wid = (blockIdx.x * blockDim.x + threadIdx.x) >> 6;
    const int nw = (gridDim.x * blockDim.x) >> 6;
    for (int e = wid; e < E; e += nw) {
        float w = ew[e];
        if (w == 0.0f) continue;
        int s = src[e], t = tgt[e];
        const float* d = (w > 0.0f) ? dinvp : dinvn;
        const float* h = (w > 0.0f) ? hp : hn;
        float norm = d[s] * w * d[t];
        const float* hs = h + (size_t)s * F;
        float* dst = agg + (size_t)t * F;
        if (F == 128) {
            float2 v = ((const float2*)hs)[lane];
            atomicAdd(dst + 2*lane,     v.x * norm);
            atomicAdd(dst + 2*lane + 1, v.y * norm);
        } else {
            atomicAdd(dst + lane, hs[lane] * norm);
        }
    }
}

// ---------------------------------------------------------------------------
// out = relu(agg + hp*dinvp^2 + bp - hn*dinvn^2 - bn)   (out may alias agg)
// ---------------------------------------------------------------------------
template<int F>
__global__ void combine_kernel(const float* agg,
                               const float* __restrict__ hp, const float* __restrict__ hn,
                               const float* __restrict__ dinvp, const float* __restrict__ dinvn,
                               const float* __restrict__ bp, const float* __restrict__ bn,
                               float* out, int n) {
    size_t i = (size_t)blockIdx.x * blockDim.x + threadIdx.x;
    if (i >= (size_t)n * F) return;
    int row = (int)(i / F);
    int c   = (int)(i % F);
    float dp = dinvp[row], dn = dinvn[row];
    float v = agg[i] + hp[i] * (dp * dp) + bp[c] - hn[i] * (dn * dn) - bn[c];
    out[i] = v > 0.0f ? v : 0.0f;
}

// ---------------------------------------------------------------------------
extern "C" void kernel_launch(void* const* d_in, const int* in_sizes, int n_in,
                              void* d_out, int out_size, void* d_ws, size_t ws_size,
                              hipStream_t stream) {
    const float* x   = (const float*)d_in[0];
    const int*   ei  = (const int*)d_in[1];
    const float* ew  = (const float*)d_in[2];
    const float* W1p = (const float*)d_in[3];
    const float* b1p = (const float*)d_in[4];
    const float* W1n = (const float*)d_in[5];
    const float* b1n = (const float*)d_in[6];
    const float* W2p = (const float*)d_in[7];
    const float* b2p = (const float*)d_in[8];
    const float* W2n = (const float*)d_in[9];
    const float* b2n = (const float*)d_in[10];
    float* out = (float*)d_out;

    const int E = in_sizes[2];
    const int n = in_sizes[0] / 64;  // IN = 64
    const int* src = ei;
    const int* tgt = ei + E;

    // workspace layout (floats):
    //   degp [n] | degn [n] | hp1 [n*128] | hn1 [n*128] | agg1/h [n*128]
    //   layer2 reuses hp1 region for hp2[n*64], hn2[n*64]
    float* ws   = (float*)d_ws;
    float* degp = ws;
    float* degn = ws + n;
    float* hp1  = ws + 2 * (size_t)n;
    float* hn1  = hp1 + (size_t)n * 128;
    float* agg1 = hn1 + (size_t)n * 128;
    float* hp2  = hp1;
    float* hn2  = hp1 + (size_t)n * 64;

    hipMemsetAsync(degp, 0, 2 * (size_t)n * sizeof(float), stream);
    hipMemsetAsync(agg1, 0, (size_t)n * 128 * sizeof(float), stream);
    hipMemsetAsync(out,  0, (size_t)n * 64 * sizeof(float), stream);

    deg_kernel<<<(E + TPB - 1) / TPB, TPB, 0, stream>>>(tgt, ew, degp, degn, E);
    dinv_kernel<<<(n + TPB - 1) / TPB, TPB, 0, stream>>>(degp, degn, n);

    // ---- layer 1: IN=64 -> H=128 ----
    {
        dim3 g((n + TPB - 1) / TPB, 2);
        dual_gemm_kernel<64, 128><<<g, TPB, 0, stream>>>(x, W1p, W1n, hp1, hn1, n);
    }
    scatter_kernel<128><<<8192, TPB, 0, stream>>>(src, tgt, ew, degp, degn, hp1, hn1, agg1, E);
    combine_kernel<128><<<(int)(((size_t)n * 128 + TPB - 1) / TPB), TPB, 0, stream>>>(
        agg1, hp1, hn1, degp, degn, b1p, b1n, agg1, n);  // h written in place into agg1

    // ---- layer 2: H=128 -> OUT=64 ----
    {
        dim3 g((n + TPB - 1) / TPB, 2);
        dual_gemm_kernel<128, 64><<<g, TPB, 0, stream>>>(agg1, W2p, W2n, hp2, hn2, n);
    }
    scatter_kernel<64><<<8192, TPB, 0, stream>>>(src, tgt, ew, degp, degn, hp2, hn2, out, E);
    combine_kernel<64><<<(int)(((size_t)n * 64 + TPB - 1) / TPB), TPB, 0, stream>>>(
        out, hp2, hn2, degp, degn, b2p, b2n, out, n);
}

// Round 2
// 1232.743 us; speedup vs baseline: 1.9541x; 1.9541x over previous
//
#include <hip/hip_runtime.h>
#include <cstddef>

#define TPB 256
#define SCAN_T 1024

// ---------------------------------------------------------------------------
// Histogram + degree: count[t]++, degp[t]+=max(w,0), degn[t]+=max(-w,0)
// ---------------------------------------------------------------------------
__global__ void hist_kernel(const int* __restrict__ tgt, const float* __restrict__ ew,
                            int* __restrict__ cnt, float* __restrict__ degp,
                            float* __restrict__ degn, int E) {
    int e = blockIdx.x * blockDim.x + threadIdx.x;
    if (e >= E) return;
    int t = tgt[e];
    float w = ew[e];
    atomicAdd(&cnt[t], 1);
    if (w > 0.0f)      atomicAdd(&degp[t], w);
    else if (w < 0.0f) atomicAdd(&degn[t], -w);
}

// dinv = rsqrt(deg + 1) in place (deg >= 0, so always > 0)
__global__ void dinv_kernel(float* __restrict__ degp, float* __restrict__ degn, int n) {
    int i = blockIdx.x * blockDim.x + threadIdx.x;
    if (i >= n) return;
    degp[i] = rsqrtf(degp[i] + 1.0f);
    degn[i] = rsqrtf(degn[i] + 1.0f);
}

// ---------------------------------------------------------------------------
// Single-block exclusive scan: rowstart[0..n] from cnt[0..n)
// ---------------------------------------------------------------------------
__global__ void scan_kernel(const int* __restrict__ cnt, int* __restrict__ rowstart, int n) {
    __shared__ int sm[SCAN_T];
    __shared__ int carry;
    int tid = threadIdx.x;
    if (tid == 0) carry = 0;
    __syncthreads();
    for (int base = 0; base < n; base += SCAN_T) {
        int i = base + tid;
        int v = (i < n) ? cnt[i] : 0;
        sm[tid] = v;
        __syncthreads();
        for (int off = 1; off < SCAN_T; off <<= 1) {
            int add = (tid >= off) ? sm[tid - off] : 0;
            __syncthreads();
            sm[tid] += add;
            __syncthreads();
        }
        int c = carry;
        if (i < n) rowstart[i] = c + sm[tid] - v;
        __syncthreads();
        if (tid == 0) carry = c + sm[SCAN_T - 1];
        __syncthreads();
    }
    if (tid == 0) rowstart[n] = carry;
}

// ---------------------------------------------------------------------------
// Fill CSR payload: edat[slot] = {(src<<1)|negflag, bitcast(norm)}
// norm carries the sign: w<0 edges store dinvn[s]*w*dinvn[t] (negative),
// so a single accumulator handles pos-add and neg-subtract.
// ---------------------------------------------------------------------------
__global__ void fill_kernel(const int* __restrict__ src, const int* __restrict__ tgt,
                            const float* __restrict__ ew,
                            const float* __restrict__ dinvp, const float* __restrict__ dinvn,
                            const int* __restrict__ rowstart, int* __restrict__ cursor,
                            int2* __restrict__ edat, int E) {
    int e = blockIdx.x * blockDim.x + threadIdx.x;
    if (e >= E) return;
    int t = tgt[e], s = src[e];
    float w = ew[e];
    int pos = atomicAdd(&cursor[t], 1);
    int slot = rowstart[t] + pos;
    float nv; int flag;
    if (w >= 0.0f) { nv = dinvp[s] * w * dinvp[t]; flag = 0; }
    else           { nv = dinvn[s] * w * dinvn[t]; flag = 1; }
    edat[slot] = make_int2((s << 1) | flag, __float_as_int(nv));
}

// ---------------------------------------------------------------------------
// Dual GEMM: hp = x @ Wp^T, hn = x @ Wn^T.  W is [OUTF, IN] row-major.
// One thread per row; x row in VGPRs; W via wave-uniform (scalar) loads.
// ---------------------------------------------------------------------------
template<int IN, int OUTF>
__global__ void dual_gemm_kernel(const float* __restrict__ x,
                                 const float* __restrict__ Wp, const float* __restrict__ Wn,
                                 float* __restrict__ hp, float* __restrict__ hn, int n) {
    int row = blockIdx.x * blockDim.x + threadIdx.x;
    if (row >= n) return;
    float xr[IN];
    const float4* xp = (const float4*)(x + (size_t)row * IN);
#pragma unroll
    for (int q = 0; q < IN / 4; ++q) {
        float4 v = xp[q];
        xr[4*q+0] = v.x; xr[4*q+1] = v.y; xr[4*q+2] = v.z; xr[4*q+3] = v.w;
    }
    const int c_begin = blockIdx.y * (OUTF / 2);
    const int c_end   = c_begin + (OUTF / 2);
    for (int c = c_begin; c < c_end; c += 4) {
        float ap0 = 0.f, ap1 = 0.f, ap2 = 0.f, ap3 = 0.f;
        float an0 = 0.f, an1 = 0.f, an2 = 0.f, an3 = 0.f;
#pragma unroll 16
        for (int k = 0; k < IN; ++k) {
            float xv = xr[k];
            ap0 += xv * Wp[(size_t)(c+0)*IN + k];
            ap1 += xv * Wp[(size_t)(c+1)*IN + k];
            ap2 += xv * Wp[(size_t)(c+2)*IN + k];
            ap3 += xv * Wp[(size_t)(c+3)*IN + k];
            an0 += xv * Wn[(size_t)(c+0)*IN + k];
            an1 += xv * Wn[(size_t)(c+1)*IN + k];
            an2 += xv * Wn[(size_t)(c+2)*IN + k];
            an3 += xv * Wn[(size_t)(c+3)*IN + k];
        }
        float4 op = {ap0, ap1, ap2, ap3};
        float4 on = {an0, an1, an2, an3};
        *(float4*)(hp + (size_t)row * OUTF + c) = op;
        *(float4*)(hn + (size_t)row * OUTF + c) = on;
    }
}

// ---------------------------------------------------------------------------
// Gather, F=128: one wave per target node. acc += h[src]*norm over in-edges,
// fused epilogue: relu(acc + hp[t]*dp^2 + bp - hn[t]*dn^2 - bn).
// ---------------------------------------------------------------------------
__global__ __launch_bounds__(256) void gather128_kernel(
        const int* __restrict__ rowstart, const int2* __restrict__ edat,
        const float* __restrict__ hp, const float* __restrict__ hn,
        const float* __restrict__ dinvp, const float* __restrict__ dinvn,
        const float* __restrict__ bp, const float* __restrict__ bn,
        float* __restrict__ out, int n) {
    const int lane = threadIdx.x & 63;
    int t = (blockIdx.x * blockDim.x + threadIdx.x) >> 6;
    if (t >= n) return;
    int beg = rowstart[t], end = rowstart[t + 1];
    float2 acc0 = {0.f, 0.f}, acc1 = {0.f, 0.f};
    int e = beg;
    for (; e + 1 < end; e += 2) {
        int2 d0 = edat[e], d1 = edat[e + 1];
        float nv0 = __int_as_float(d0.y), nv1 = __int_as_float(d1.y);
        const float* h0 = (d0.x & 1) ? hn : hp;
        const float* h1 = (d1.x & 1) ? hn : hp;
        float2 v0 = *(const float2*)(h0 + (((size_t)(d0.x >> 1)) << 7) + 2 * lane);
        float2 v1 = *(const float2*)(h1 + (((size_t)(d1.x >> 1)) << 7) + 2 * lane);
        acc0.x += v0.x * nv0; acc0.y += v0.y * nv0;
        acc1.x += v1.x * nv1; acc1.y += v1.y * nv1;
    }
    if (e < end) {
        int2 d0 = edat[e];
        float nv0 = __int_as_float(d0.y);
        const float* h0 = (d0.x & 1) ? hn : hp;
        float2 v0 = *(const float2*)(h0 + (((size_t)(d0.x >> 1)) << 7) + 2 * lane);
        acc0.x += v0.x * nv0; acc0.y += v0.y * nv0;
    }
    float dp = dinvp[t], dn = dinvn[t];
    float sp = dp * dp, sn = dn * dn;
    size_t base = ((size_t)t << 7) + 2 * lane;
    float2 hpv = *(const float2*)(hp + base);
    float2 hnv = *(const float2*)(hn + base);
    float o0 = acc0.x + acc1.x + hpv.x * sp + bp[2*lane]   - hnv.x * sn - bn[2*lane];
    float o1 = acc0.y + acc1.y + hpv.y * sp + bp[2*lane+1] - hnv.y * sn - bn[2*lane+1];
    float2 r = make_float2(fmaxf(o0, 0.f), fmaxf(o1, 0.f));
    *(float2*)(out + base) = r;
}

// Gather, F=64: one wave per target node, one float per lane.
__global__ __launch_bounds__(256) void gather64_kernel(
        const int* __restrict__ rowstart, const int2* __restrict__ edat,
        const float* __restrict__ hp, const float* __restrict__ hn,
        const float* __restrict__ dinvp, const float* __restrict__ dinvn,
        const float* __restrict__ bp, const float* __restrict__ bn,
        float* __restrict__ out, int n) {
    const int lane = threadIdx.x & 63;
    int t = (blockIdx.x * blockDim.x + threadIdx.x) >> 6;
    if (t >= n) return;
    int beg = rowstart[t], end = rowstart[t + 1];
    float acc0 = 0.f, acc1 = 0.f;
    int e = beg;
    for (; e + 1 < end; e += 2) {
        int2 d0 = edat[e], d1 = edat[e + 1];
        float nv0 = __int_as_float(d0.y), nv1 = __int_as_float(d1.y);
        const float* h0 = (d0.x & 1) ? hn : hp;
        const float* h1 = (d1.x & 1) ? hn : hp;
        float v0 = h0[(((size_t)(d0.x >> 1)) << 6) + lane];
        float v1 = h1[(((size_t)(d1.x >> 1)) << 6) + lane];
        acc0 += v0 * nv0;
        acc1 += v1 * nv1;
    }
    if (e < end) {
        int2 d0 = edat[e];
        float nv0 = __int_as_float(d0.y);
        acc0 += ((d0.x & 1) ? hn : hp)[(((size_t)(d0.x >> 1)) << 6) + lane] * nv0;
    }
    float dp = dinvp[t], dn = dinvn[t];
    size_t base = ((size_t)t << 6) + lane;
    float o = acc0 + acc1 + hp[base] * (dp * dp) + bp[lane] - hn[base] * (dn * dn) - bn[lane];
    out[base] = fmaxf(o, 0.f);
}

// ---------------------------------------------------------------------------
extern "C" void kernel_launch(void* const* d_in, const int* in_sizes, int n_in,
                              void* d_out, int out_size, void* d_ws, size_t ws_size,
                              hipStream_t stream) {
    const float* x   = (const float*)d_in[0];
    const int*   ei  = (const int*)d_in[1];
    const float* ew  = (const float*)d_in[2];
    const float* W1p = (const float*)d_in[3];
    const float* b1p = (const float*)d_in[4];
    const float* W1n = (const float*)d_in[5];
    const float* b1n = (const float*)d_in[6];
    const float* W2p = (const float*)d_in[7];
    const float* b2p = (const float*)d_in[8];
    const float* W2n = (const float*)d_in[9];
    const float* b2n = (const float*)d_in[10];

    const int E = in_sizes[2];
    const int n = in_sizes[0] / 64;  // IN = 64
    const int* src = ei;
    const int* tgt = ei + E;

    // ws layout (floats): degp[n] | degn[n] | hp1[128n] | hn1[128n] | h[128n]
    // layer2: hp2/hn2 overwrite hp1 region; out2 uses hn1 region.
    float* ws   = (float*)d_ws;
    float* degp = ws;
    float* degn = ws + n;
    float* hp1  = ws + 2 * (size_t)n;
    float* hn1  = hp1 + (size_t)n * 128;
    float* h    = hn1 + (size_t)n * 128;
    float* hp2  = hp1;
    float* hn2  = hp1 + (size_t)n * 64;
    float* out2 = hn1;

    // CSR parked in d_out (25.6 MB; CSR needs ~14 MB; d_out written last)
    int*  cnt      = (int*)d_out;
    int*  cursor   = cnt + n;
    int*  rowstart = cnt + 2 * n;          // n+1 entries
    int2* edat     = (int2*)(cnt + 3 * n + 2);  // 8B-aligned (3n+2 even)

    hipMemsetAsync(cnt, 0, 2 * (size_t)n * sizeof(int), stream);      // cnt + cursor
    hipMemsetAsync(degp, 0, 2 * (size_t)n * sizeof(float), stream);   // degp + degn

    const int gridE = (E + TPB - 1) / TPB;
    const int gridN = (n + TPB - 1) / TPB;
    const int gridW = (n * 64 + TPB - 1) / TPB;  // one wave per node

    hist_kernel<<<gridE, TPB, 0, stream>>>(tgt, ew, cnt, degp, degn, E);
    dinv_kernel<<<gridN, TPB, 0, stream>>>(degp, degn, n);
    scan_kernel<<<1, SCAN_T, 0, stream>>>(cnt, rowstart, n);
    fill_kernel<<<gridE, TPB, 0, stream>>>(src, tgt, ew, degp, degn, rowstart, cursor, edat, E);

    // ---- layer 1: IN=64 -> H=128 ----
    {
        dim3 g(gridN, 2);
        dual_gemm_kernel<64, 128><<<g, TPB, 0, stream>>>(x, W1p, W1n, hp1, hn1, n);
    }
    gather128_kernel<<<gridW, TPB, 0, stream>>>(rowstart, edat, hp1, hn1, degp, degn,
                                                b1p, b1n, h, n);

    // ---- layer 2: H=128 -> OUT=64 ----
    {
        dim3 g(gridN, 2);
        dual_gemm_kernel<128, 64><<<g, TPB, 0, stream>>>(h, W2p, W2n, hp2, hn2, n);
    }
    gather64_kernel<<<gridW, TPB, 0, stream>>>(rowstart, edat, hp2, hn2, degp, degn,
                                               b2p, b2n, out2, n);

    hipMemcpyAsync(d_out, out2, (size_t)n * 64 * sizeof(float),
                   hipMemcpyDeviceToDevice, stream);
}